// Round 5
// baseline (690.800 us; speedup 1.0000x reference)
//
#include <hip/hip_runtime.h>
#include <hip/hip_bf16.h>

#define LOG2F_ 0.69314718055994530942f

typedef __attribute__((ext_vector_type(8))) short s8bf;   // 8 bf16 (4 VGPRs)
typedef __attribute__((ext_vector_type(4))) float f32x4;  // MFMA C/D

// softplus(x) - log(2), numerically stable
__device__ __forceinline__ float ssp(float x) {
    float e = __expf(-fabsf(x));
    return __logf(1.0f + e) + fmaxf(x, 0.0f) - LOG2F_;
}
__device__ __forceinline__ short bf_hi(float x) {
    __hip_bfloat16 h = __float2bfloat16(x);
    return *reinterpret_cast<short*>(&h);
}
__device__ __forceinline__ float bf_to_f(short s) {
    __hip_bfloat16 h;
    *reinterpret_cast<short*>(&h) = s;
    return __bfloat162float(h);
}

// ---- sort pipeline: histogram -> exclusive scan -> rank ----
__global__ __launch_bounds__(256) void hist_kernel(const int* __restrict__ dst,
                                                   int* __restrict__ hist, int E) {
    int i = blockIdx.x * blockDim.x + threadIdx.x;
    if (i < E) atomicAdd(&hist[dst[i]], 1);
}

__global__ __launch_bounds__(1024) void scan_kernel(const int* __restrict__ hist,
                                                    int* __restrict__ cursor, int N) {
    __shared__ int tot[1024];
    const int tid = threadIdx.x;
    const int chunk = (N + 1023) >> 10;
    const int s = tid * chunk;
    const int e = min(s + chunk, N);
    int sum = 0;
    for (int i = s; i < e; ++i) sum += hist[i];
    tot[tid] = sum;
    __syncthreads();
    if (tid == 0) {
        int run = 0;
        for (int i = 0; i < 1024; ++i) { int t = tot[i]; tot[i] = run; run += t; }
    }
    __syncthreads();
    int run = tot[tid];
    for (int i = s; i < e; ++i) { cursor[i] = run; run += hist[i]; }
}

__global__ __launch_bounds__(256) void rank_kernel(const int* __restrict__ dst,
                                                   int* __restrict__ cursor,
                                                   int* __restrict__ order, int E) {
    int i = blockIdx.x * blockDim.x + threadIdx.x;
    if (i < E) {
        int p = atomicAdd(&cursor[dst[i]], 1);
        order[p] = i;
    }
}

// ---- edge filter network over SORTED edges, segmented-reduce scatter ----
// LDS: 16KB = 4 waves x 4KB (Xh/Xl bf16 -> overlaid by h1 f32 -> overlaid by w f32).
// Weight bf16x2-split fragments live in registers/AGPRs (R3 layout).
__global__ __launch_bounds__(256, 2) void edge_kernel(
    const float* __restrict__ bf, const float* __restrict__ eh,
    const float* __restrict__ W1, const float* __restrict__ b1,
    const float* __restrict__ W2, const float* __restrict__ b2,
    const int* __restrict__ dst, const int* __restrict__ order,
    float* __restrict__ sums, int E)
{
    __shared__ __align__(16) unsigned char lds[16384];

    const int tid  = threadIdx.x;
    const int lane = tid & 63;
    const int wv   = tid >> 6;
    const int g    = lane >> 4;     // 16-lane group 0..3
    const int n16  = lane & 15;

    // ---- init: build W1/W2 bf16-split B-fragments in registers ----
    s8bf w1h[4][2], w1l[4][2], w2h[4][2], w2l[4][2];
    {
        float* wst = (float*)lds;   // 16KB staging (pre-loop only)
        for (int i = tid; i < 4096; i += 256) wst[i] = W1[i];
        __syncthreads();
        #pragma unroll
        for (int nt = 0; nt < 4; ++nt)
            #pragma unroll
            for (int k0i = 0; k0i < 2; ++k0i)
                #pragma unroll
                for (int j = 0; j < 8; ++j) {
                    float v = wst[(k0i * 32 + g * 8 + j) * 64 + nt * 16 + n16];
                    short h = bf_hi(v);
                    w1h[nt][k0i][j] = h;
                    w1l[nt][k0i][j] = bf_hi(v - bf_to_f(h));
                }
        __syncthreads();
        for (int i = tid; i < 4096; i += 256) wst[i] = W2[i];
        __syncthreads();
        #pragma unroll
        for (int nt = 0; nt < 4; ++nt)
            #pragma unroll
            for (int k0i = 0; k0i < 2; ++k0i)
                #pragma unroll
                for (int j = 0; j < 8; ++j) {
                    float v = wst[(k0i * 32 + g * 8 + j) * 64 + nt * 16 + n16];
                    short h = bf_hi(v);
                    w2h[nt][k0i][j] = h;
                    w2l[nt][k0i][j] = bf_hi(v - bf_to_f(h));
                }
        __syncthreads();   // last barrier — main loop is barrier-free
    }

    float b1v[4], b2v[4];
    #pragma unroll
    for (int nt = 0; nt < 4; ++nt) { b1v[nt] = b1[nt*16 + n16]; b2v[nt] = b2[nt*16 + n16]; }

    unsigned char* wbase = lds + (wv << 12);   // 4KB per wave
    char* Xh = (char*)wbase;                    // [16 rows][128B] swizzled bf16
    char* Xl = (char*)wbase + 2048;

    const int r4   = lane >> 2;          // staging row 0..15
    const int c16  = (lane & 3) << 4;    // staging col base
    const int s0   = (lane & 3) << 1;    // 16B slot base
    const int crow = g << 2;             // C-frag row base
    const int swz_n = (n16 & 7) << 4;

    const int wave_id = (blockIdx.x << 2) + wv;
    const int nwaves  = gridDim.x << 2;
    const int ntiles  = (E + 15) >> 4;

    // prologue: gather first tile's bf rows (order -> bf pointer chase)
    float xs[16];
    {
        const int t0 = wave_id;
        const int p0 = (t0 << 4) + r4;
        if (t0 < ntiles && p0 < E) {
            const size_t roff = (size_t)order[p0] * 64 + c16;
            *(float4*)&xs[0]  = *(const float4*)(bf + roff);
            *(float4*)&xs[4]  = *(const float4*)(bf + roff + 4);
            *(float4*)&xs[8]  = *(const float4*)(bf + roff + 8);
            *(float4*)&xs[12] = *(const float4*)(bf + roff + 12);
        } else {
            #pragma unroll
            for (int j = 0; j < 16; ++j) xs[j] = 0.f;
        }
    }

    for (int t = wave_id; t < ntiles; t += nwaves) {
        const int base = t << 4;

        // ---- split current X, stage to LDS ----
        s8bf hv0, hv1, lv0, lv1;
        #pragma unroll
        for (int j = 0; j < 8; ++j) {
            short h  = bf_hi(xs[j]);      hv0[j] = h;  lv0[j] = bf_hi(xs[j]     - bf_to_f(h));
            short h2 = bf_hi(xs[8 + j]);  hv1[j] = h2; lv1[j] = bf_hi(xs[8 + j] - bf_to_f(h2));
        }
        {
            const int sw = (r4 & 7) << 4;
            const int a0 = r4 * 128 + ((s0 << 4) ^ sw);
            const int a1 = r4 * 128 + (((s0 + 1) << 4) ^ sw);
            *(s8bf*)(Xh + a0) = hv0;  *(s8bf*)(Xh + a1) = hv1;
            *(s8bf*)(Xl + a0) = lv0;  *(s8bf*)(Xl + a1) = lv1;
        }

        // ---- tile metadata: sorted edge ids + dst (lane<16), broadcast later ----
        int eiv = 0, dvec = -1;
        if (lane < 16 && base + lane < E) {
            eiv  = order[base + lane];
            dvec = dst[eiv];
        }

        // ---- prefetch next tile's bf (covers whole iteration) ----
        {
            const int tn = t + nwaves;
            if (tn < ntiles) {
                const int pn = (tn << 4) + r4;
                if (pn < E) {
                    const size_t roff = (size_t)order[pn] * 64 + c16;
                    *(float4*)&xs[0]  = *(const float4*)(bf + roff);
                    *(float4*)&xs[4]  = *(const float4*)(bf + roff + 4);
                    *(float4*)&xs[8]  = *(const float4*)(bf + roff + 8);
                    *(float4*)&xs[12] = *(const float4*)(bf + roff + 12);
                } else {
                    #pragma unroll
                    for (int j = 0; j < 16; ++j) xs[j] = 0.f;
                }
            }
        }

        // ---- gather eh rows for this tile into registers ----
        float evs[16];
        #pragma unroll
        for (int e = 0; e < 16; ++e) {
            int ei = __shfl(eiv, e, 64);
            evs[e] = (base + e < E) ? eh[(size_t)ei * 64 + lane] : 0.f;
        }

        // ---- matmul 1: X @ W1 (hh + hl + lh) ----
        f32x4 acc[4];
        #pragma unroll
        for (int nt = 0; nt < 4; ++nt) acc[nt] = (f32x4){0.f, 0.f, 0.f, 0.f};
        #pragma unroll
        for (int k0i = 0; k0i < 2; ++k0i) {
            const int sA = (k0i << 2) + g;
            const int ab = n16 * 128 + ((sA << 4) ^ swz_n);
            s8bf ah = *(s8bf*)(Xh + ab);
            s8bf al = *(s8bf*)(Xl + ab);
            #pragma unroll
            for (int nt = 0; nt < 4; ++nt) {
                acc[nt] = __builtin_amdgcn_mfma_f32_16x16x32_bf16(ah, w1h[nt][k0i], acc[nt], 0, 0, 0);
                acc[nt] = __builtin_amdgcn_mfma_f32_16x16x32_bf16(ah, w1l[nt][k0i], acc[nt], 0, 0, 0);
                acc[nt] = __builtin_amdgcn_mfma_f32_16x16x32_bf16(al, w1h[nt][k0i], acc[nt], 0, 0, 0);
            }
        }

        // ---- h1 = ssp(acc + b1) -> f32 LDS swizzled (overlays Xh/Xl) ----
        #pragma unroll
        for (int nt = 0; nt < 4; ++nt)
            #pragma unroll
            for (int r = 0; r < 4; ++r) {
                float h = ssp(acc[nt][r] + b1v[nt]);
                const int row = crow + r;
                *(float*)((char*)wbase + row * 256 + ((((nt * 16 + n16) << 2)) ^ ((row & 7) << 4))) = h;
            }

        // ---- matmul 2: h1 @ W2 (split A rebuilt from f32) ----
        f32x4 acc2[4];
        #pragma unroll
        for (int nt = 0; nt < 4; ++nt) acc2[nt] = (f32x4){0.f, 0.f, 0.f, 0.f};
        #pragma unroll
        for (int k0i = 0; k0i < 2; ++k0i) {
            const int bc = (k0i << 7) + (g << 5);
            const int rb = n16 << 8;
            f32x4 f0 = *(f32x4*)((char*)wbase + rb + (bc ^ swz_n));
            f32x4 f1 = *(f32x4*)((char*)wbase + rb + ((bc + 16) ^ swz_n));
            s8bf ah, al;
            #pragma unroll
            for (int j = 0; j < 4; ++j) {
                short h  = bf_hi(f0[j]); ah[j]     = h;  al[j]     = bf_hi(f0[j] - bf_to_f(h));
                short h2 = bf_hi(f1[j]); ah[4 + j] = h2; al[4 + j] = bf_hi(f1[j] - bf_to_f(h2));
            }
            #pragma unroll
            for (int nt = 0; nt < 4; ++nt) {
                acc2[nt] = __builtin_amdgcn_mfma_f32_16x16x32_bf16(ah, w2h[nt][k0i], acc2[nt], 0, 0, 0);
                acc2[nt] = __builtin_amdgcn_mfma_f32_16x16x32_bf16(ah, w2l[nt][k0i], acc2[nt], 0, 0, 0);
                acc2[nt] = __builtin_amdgcn_mfma_f32_16x16x32_bf16(al, w2h[nt][k0i], acc2[nt], 0, 0, 0);
            }
        }

        // ---- w = ssp(acc2 + b2) -> [16][256B] f32 swizzled (overlays h1) ----
        #pragma unroll
        for (int nt = 0; nt < 4; ++nt)
            #pragma unroll
            for (int r = 0; r < 4; ++r) {
                const int row = crow + r;
                *(float*)((char*)wbase + (row << 8) +
                          ((((nt * 16 + n16) << 2)) ^ ((row & 7) << 4))) =
                    ssp(acc2[nt][r] + b2v[nt]);
            }

        // ---- scatter: segmented reduce over sorted dst runs ----
        // dst values are sorted within the tile -> accumulate runs in a register,
        // one row-atomic per distinct node (~1.5 per tile instead of 16).
        float accv = 0.f;
        int cur = -1;
        #pragma unroll
        for (int e = 0; e < 16; ++e) {
            if (base + e < E) {                       // wave-uniform
                int d = __shfl(dvec, e, 64);          // uniform
                float mv = *(float*)((char*)wbase + (e << 8) +
                                     ((lane << 2) ^ ((e & 7) << 4))) * evs[e];
                bool nw = (d != cur);                 // uniform
                if (nw && cur >= 0)
                    atomicAdd(&sums[(size_t)cur * 64 + lane], accv);
                accv = nw ? mv : (accv + mv);
                cur = d;
            }
        }
        if (cur >= 0) atomicAdd(&sums[(size_t)cur * 64 + lane], accv);
    }
}

// ---- node interaction block: h = sums/max(deg,1); out = ssp(h@W3+b3) ----
__global__ __launch_bounds__(256) void node_kernel(
    const float* __restrict__ sums, const int* __restrict__ hist,
    const float* __restrict__ W3, const float* __restrict__ b3,
    float* __restrict__ out, int N)
{
    __shared__ float sW[64][64];
    __shared__ float sb[64];
    __shared__ float sC[64];
    __shared__ float sX[64][65];

    const int tid = threadIdx.x;
    for (int i = tid; i < 4096; i += 256) sW[i >> 6][i & 63] = W3[i];
    if (tid < 64) sb[tid] = b3[tid];

    const int f4 = (tid & 15) << 2;
    const int e4 = (tid >> 4) << 2;
    const int ntiles = (N + 63) >> 6;

    for (int t = blockIdx.x; t < ntiles; t += gridDim.x) {
        const int base = t << 6;
        __syncthreads();
        if (tid < 64) {
            int gn = base + tid;
            sC[tid] = (gn < N) ? 1.0f / fmaxf((float)hist[gn], 1.0f) : 0.0f;
        }
        __syncthreads();
        #pragma unroll
        for (int k = 0; k < 16; ++k) {
            int idx = (k << 8) + tid;
            int n = idx >> 6, r = idx & 63;
            int gn = base + n;
            sX[n][r] = (gn < N) ? sums[(size_t)gn * 64 + r] * sC[n] : 0.0f;
        }
        __syncthreads();

        float acc[4][4] = {{0.f,0.f,0.f,0.f},{0.f,0.f,0.f,0.f},
                           {0.f,0.f,0.f,0.f},{0.f,0.f,0.f,0.f}};
        #pragma unroll 8
        for (int r = 0; r < 64; ++r) {
            float xv[4];
            #pragma unroll
            for (int i = 0; i < 4; ++i) xv[i] = sX[e4 + i][r];
            float4 w4 = *(const float4*)&sW[r][f4];
            #pragma unroll
            for (int i = 0; i < 4; ++i) {
                acc[i][0] = fmaf(xv[i], w4.x, acc[i][0]);
                acc[i][1] = fmaf(xv[i], w4.y, acc[i][1]);
                acc[i][2] = fmaf(xv[i], w4.z, acc[i][2]);
                acc[i][3] = fmaf(xv[i], w4.w, acc[i][3]);
            }
        }

        #pragma unroll
        for (int i = 0; i < 4; ++i) {
            int gn = base + e4 + i;
            if (gn < N) {
                float4 o;
                o.x = ssp(acc[i][0] + sb[f4 + 0]);
                o.y = ssp(acc[i][1] + sb[f4 + 1]);
                o.z = ssp(acc[i][2] + sb[f4 + 2]);
                o.w = ssp(acc[i][3] + sb[f4 + 3]);
                *(float4*)&out[(size_t)gn * 64 + f4] = o;
            }
        }
    }
}

extern "C" void kernel_launch(void* const* d_in, const int* in_sizes, int n_in,
                              void* d_out, int out_size, void* d_ws, size_t ws_size,
                              hipStream_t stream) {
    const float* bf = (const float*)d_in[0];
    const float* eh = (const float*)d_in[1];
    const float* W1 = (const float*)d_in[2];
    const float* b1 = (const float*)d_in[3];
    const float* W2 = (const float*)d_in[4];
    const float* b2 = (const float*)d_in[5];
    const float* W3 = (const float*)d_in[6];
    const float* b3 = (const float*)d_in[7];
    const int*   dst = (const int*)d_in[8];

    const int E = in_sizes[0] / 64;
    const int N = out_size / 64;        // out is [N, 64]

    // workspace layout: sums [N*64 f32] | hist [N i32] | cursor [N i32] | order [E i32]
    float* sums   = (float*)d_ws;
    int*   hist   = (int*)(sums + (size_t)N * 64);
    int*   cursor = hist + N;
    int*   order  = cursor + N;

    // zero sums + hist (cursor/order fully written by scan/rank)
    hipMemsetAsync(d_ws, 0, (size_t)N * 64 * sizeof(float) + N * sizeof(int), stream);

    const int gE = (E + 255) / 256;
    hist_kernel<<<gE, 256, 0, stream>>>(dst, hist, E);
    scan_kernel<<<1, 1024, 0, stream>>>(hist, cursor, N);
    rank_kernel<<<gE, 256, 0, stream>>>(dst, cursor, order, E);

    edge_kernel<<<2048, 256, 0, stream>>>(bf, eh, W1, b1, W2, b2, dst, order, sums, E);

    const int ntilesN = (N + 63) >> 6;
    node_kernel<<<ntilesN, 256, 0, stream>>>(sums, hist, W3, b3, (float*)d_out, N);
}

// Round 6
// 686.117 us; speedup vs baseline: 1.0068x; 1.0068x over previous
//
#include <hip/hip_runtime.h>
#include <hip/hip_bf16.h>

#define LOG2F_ 0.69314718055994530942f

typedef __attribute__((ext_vector_type(8))) short s8bf;   // 8 bf16 (4 VGPRs)
typedef __attribute__((ext_vector_type(4))) float f32x4;  // MFMA C/D

// softplus(x) - log(2), numerically stable
__device__ __forceinline__ float ssp(float x) {
    float e = __expf(-fabsf(x));
    return __logf(1.0f + e) + fmaxf(x, 0.0f) - LOG2F_;
}
__device__ __forceinline__ short bf_hi(float x) {
    __hip_bfloat16 h = __float2bfloat16(x);
    return *reinterpret_cast<short*>(&h);
}
__device__ __forceinline__ float bf_to_f(short s) {
    __hip_bfloat16 h;
    *reinterpret_cast<short*>(&h) = s;
    return __bfloat162float(h);
}

// ---- sort pipeline: histogram -> hierarchical exclusive scan -> rank ----
__global__ __launch_bounds__(256) void hist_kernel(const int* __restrict__ dst,
                                                   int* __restrict__ hist, int E) {
    int i = blockIdx.x * blockDim.x + threadIdx.x;
    if (i < E) atomicAdd(&hist[dst[i]], 1);
}

// block partial sums over 1024-element chunks
__global__ __launch_bounds__(256) void scan_part(const int* __restrict__ h,
                                                 int* __restrict__ bsum, int N) {
    const int i0 = blockIdx.x * 1024 + threadIdx.x * 4;
    int s = 0;
    #pragma unroll
    for (int j = 0; j < 4; ++j) { int i = i0 + j; if (i < N) s += h[i]; }
    __shared__ int red[4];
    const int lane = threadIdx.x & 63, w = threadIdx.x >> 6;
    #pragma unroll
    for (int off = 32; off; off >>= 1) s += __shfl_down(s, off, 64);
    if (lane == 0) red[w] = s;
    __syncthreads();
    if (threadIdx.x == 0) bsum[blockIdx.x] = red[0] + red[1] + red[2] + red[3];
}

// exclusive scan of block sums (nb <= 64 fast path, serial fallback)
__global__ void scan_top(int* __restrict__ bsum, int nb) {
    const int lane = threadIdx.x;
    if (nb <= 64) {
        int v = (lane < nb) ? bsum[lane] : 0;
        int inc = v;
        #pragma unroll
        for (int off = 1; off < 64; off <<= 1) {
            int o = __shfl_up(inc, off, 64);
            if (lane >= off) inc += o;
        }
        if (lane < nb) bsum[lane] = inc - v;
    } else if (lane == 0) {
        int run = 0;
        for (int i = 0; i < nb; ++i) { int t = bsum[i]; bsum[i] = run; run += t; }
    }
}

// local exclusive scan + block offset -> cursor
__global__ __launch_bounds__(256) void scan_local(const int* __restrict__ h,
                                                  const int* __restrict__ bsum,
                                                  int* __restrict__ cursor, int N) {
    const int i0 = blockIdx.x * 1024 + threadIdx.x * 4;
    int v[4]; int s = 0;
    #pragma unroll
    for (int j = 0; j < 4; ++j) { int i = i0 + j; v[j] = (i < N) ? h[i] : 0; s += v[j]; }
    const int lane = threadIdx.x & 63, w = threadIdx.x >> 6;
    int inc = s;
    #pragma unroll
    for (int off = 1; off < 64; off <<= 1) {
        int o = __shfl_up(inc, off, 64);
        if (lane >= off) inc += o;
    }
    __shared__ int wsum[4];
    if (lane == 63) wsum[w] = inc;
    __syncthreads();
    int run = bsum[blockIdx.x];
    for (int i = 0; i < w; ++i) run += wsum[i];
    run += inc - s;   // exclusive prefix for this thread's 4 elements
    #pragma unroll
    for (int j = 0; j < 4; ++j) { int i = i0 + j; if (i < N) cursor[i] = run; run += v[j]; }
}

__global__ __launch_bounds__(256) void rank_kernel(const int* __restrict__ dst,
                                                   int* __restrict__ cursor,
                                                   int* __restrict__ order, int E) {
    int i = blockIdx.x * blockDim.x + threadIdx.x;
    if (i < E) {
        int p = atomicAdd(&cursor[dst[i]], 1);
        order[p] = i;
    }
}

// ---- edge filter network over SORTED edges, segmented-reduce scatter ----
// Scalar (SGPR) metadata via readfirstlane; bf+eh+meta prefetched one tile ahead.
__global__ __launch_bounds__(256, 2) void edge_kernel(
    const float* __restrict__ bf, const float* __restrict__ eh,
    const float* __restrict__ W1, const float* __restrict__ b1,
    const float* __restrict__ W2, const float* __restrict__ b2,
    const int* __restrict__ dst, const int* __restrict__ order,
    float* __restrict__ sums, int E)
{
    __shared__ __align__(16) unsigned char lds[16384];

    const int tid  = threadIdx.x;
    const int lane = tid & 63;
    const int wv   = __builtin_amdgcn_readfirstlane(tid >> 6);
    const int g    = lane >> 4;     // 16-lane group 0..3
    const int n16  = lane & 15;

    // ---- init: build W1/W2 bf16-split B-fragments in registers ----
    s8bf w1h[4][2], w1l[4][2], w2h[4][2], w2l[4][2];
    {
        float* wst = (float*)lds;   // 16KB staging (pre-loop only)
        for (int i = tid; i < 4096; i += 256) wst[i] = W1[i];
        __syncthreads();
        #pragma unroll
        for (int nt = 0; nt < 4; ++nt)
            #pragma unroll
            for (int k0i = 0; k0i < 2; ++k0i)
                #pragma unroll
                for (int j = 0; j < 8; ++j) {
                    float v = wst[(k0i * 32 + g * 8 + j) * 64 + nt * 16 + n16];
                    short h = bf_hi(v);
                    w1h[nt][k0i][j] = h;
                    w1l[nt][k0i][j] = bf_hi(v - bf_to_f(h));
                }
        __syncthreads();
        for (int i = tid; i < 4096; i += 256) wst[i] = W2[i];
        __syncthreads();
        #pragma unroll
        for (int nt = 0; nt < 4; ++nt)
            #pragma unroll
            for (int k0i = 0; k0i < 2; ++k0i)
                #pragma unroll
                for (int j = 0; j < 8; ++j) {
                    float v = wst[(k0i * 32 + g * 8 + j) * 64 + nt * 16 + n16];
                    short h = bf_hi(v);
                    w2h[nt][k0i][j] = h;
                    w2l[nt][k0i][j] = bf_hi(v - bf_to_f(h));
                }
        __syncthreads();   // last barrier — main loop is barrier-free
    }

    float b1v[4], b2v[4];
    #pragma unroll
    for (int nt = 0; nt < 4; ++nt) { b1v[nt] = b1[nt*16 + n16]; b2v[nt] = b2[nt*16 + n16]; }

    unsigned char* wbase = lds + (wv << 12);   // 4KB per wave
    char* Xh = (char*)wbase;                    // [16 rows][128B] swizzled bf16
    char* Xl = (char*)wbase + 2048;

    const int r4   = lane >> 2;          // staging row 0..15
    const int c16  = (lane & 3) << 4;    // staging col base
    const int s0   = (lane & 3) << 1;    // 16B slot base
    const int crow = g << 2;             // C-frag row base
    const int swz_n = (n16 & 7) << 4;

    const int wave_id = (blockIdx.x << 2) + wv;
    const int nwaves  = gridDim.x << 2;
    const int ntiles  = (E + 15) >> 4;
    const int lastE   = E - 1;

    float xs[16];        // next tile's bf rows
    float evs[16];       // current tile's eh value (this lane's feature)
    int   d_cur[16];     // current tile's dst per edge (SGPR)

    // ---- prologue: meta + bf + eh for first tile ----
    if (wave_id < ntiles) {
        const int b0 = wave_id << 4;
        {
            const int rowp = min(b0 + r4, lastE);
            const size_t roff = (size_t)order[rowp] * 64 + c16;
            *(float4*)&xs[0]  = *(const float4*)(bf + roff);
            *(float4*)&xs[4]  = *(const float4*)(bf + roff + 4);
            *(float4*)&xs[8]  = *(const float4*)(bf + roff + 8);
            *(float4*)&xs[12] = *(const float4*)(bf + roff + 12);
        }
        #pragma unroll
        for (int e = 0; e < 16; ++e) {
            const int p = b0 + e;
            int ei = __builtin_amdgcn_readfirstlane((p < E) ? order[p] : 0);
            d_cur[e] = __builtin_amdgcn_readfirstlane((p < E) ? dst[ei] : 0);
            evs[e] = eh[(size_t)ei * 64 + lane];
        }
    }

    for (int t = wave_id; t < ntiles; t += nwaves) {
        const int base = t << 4;

        // ---- split current X (from xs), stage to LDS ----
        s8bf hv0, hv1, lv0, lv1;
        #pragma unroll
        for (int j = 0; j < 8; ++j) {
            short h  = bf_hi(xs[j]);      hv0[j] = h;  lv0[j] = bf_hi(xs[j]     - bf_to_f(h));
            short h2 = bf_hi(xs[8 + j]);  hv1[j] = h2; lv1[j] = bf_hi(xs[8 + j] - bf_to_f(h2));
        }
        {
            const int sw = (r4 & 7) << 4;
            const int a0 = r4 * 128 + ((s0 << 4) ^ sw);
            const int a1 = r4 * 128 + (((s0 + 1) << 4) ^ sw);
            *(s8bf*)(Xh + a0) = hv0;  *(s8bf*)(Xh + a1) = hv1;
            *(s8bf*)(Xl + a0) = lv0;  *(s8bf*)(Xl + a1) = lv1;
        }

        // ---- prefetch tile t+nwaves: bf -> xs, eh -> evs_n, dst -> d_nxt ----
        const int tn = t + nwaves;
        float evs_n[16];
        int   d_nxt[16];
        if (tn < ntiles) {
            const int nb = tn << 4;
            {
                const int rowp = min(nb + r4, lastE);
                const size_t roff = (size_t)order[rowp] * 64 + c16;
                *(float4*)&xs[0]  = *(const float4*)(bf + roff);
                *(float4*)&xs[4]  = *(const float4*)(bf + roff + 4);
                *(float4*)&xs[8]  = *(const float4*)(bf + roff + 8);
                *(float4*)&xs[12] = *(const float4*)(bf + roff + 12);
            }
            #pragma unroll
            for (int e = 0; e < 16; ++e) {
                const int p = nb + e;
                int ei = __builtin_amdgcn_readfirstlane((p < E) ? order[p] : 0);
                d_nxt[e] = __builtin_amdgcn_readfirstlane((p < E) ? dst[ei] : 0);
                evs_n[e] = eh[(size_t)ei * 64 + lane];
            }
        }

        // ---- matmul 1: X @ W1 (hh + hl + lh) ----
        f32x4 acc[4];
        #pragma unroll
        for (int nt = 0; nt < 4; ++nt) acc[nt] = (f32x4){0.f, 0.f, 0.f, 0.f};
        #pragma unroll
        for (int k0i = 0; k0i < 2; ++k0i) {
            const int sA = (k0i << 2) + g;
            const int ab = n16 * 128 + ((sA << 4) ^ swz_n);
            s8bf ah = *(s8bf*)(Xh + ab);
            s8bf al = *(s8bf*)(Xl + ab);
            #pragma unroll
            for (int nt = 0; nt < 4; ++nt) {
                acc[nt] = __builtin_amdgcn_mfma_f32_16x16x32_bf16(ah, w1h[nt][k0i], acc[nt], 0, 0, 0);
                acc[nt] = __builtin_amdgcn_mfma_f32_16x16x32_bf16(ah, w1l[nt][k0i], acc[nt], 0, 0, 0);
                acc[nt] = __builtin_amdgcn_mfma_f32_16x16x32_bf16(al, w1h[nt][k0i], acc[nt], 0, 0, 0);
            }
        }

        // ---- h1 = ssp(acc + b1) -> f32 LDS swizzled (overlays Xh/Xl) ----
        #pragma unroll
        for (int nt = 0; nt < 4; ++nt)
            #pragma unroll
            for (int r = 0; r < 4; ++r) {
                float h = ssp(acc[nt][r] + b1v[nt]);
                const int row = crow + r;
                *(float*)((char*)wbase + row * 256 + ((((nt * 16 + n16) << 2)) ^ ((row & 7) << 4))) = h;
            }

        // ---- matmul 2: h1 @ W2 (split A rebuilt from f32) ----
        f32x4 acc2[4];
        #pragma unroll
        for (int nt = 0; nt < 4; ++nt) acc2[nt] = (f32x4){0.f, 0.f, 0.f, 0.f};
        #pragma unroll
        for (int k0i = 0; k0i < 2; ++k0i) {
            const int bc = (k0i << 7) + (g << 5);
            const int rb = n16 << 8;
            f32x4 f0 = *(f32x4*)((char*)wbase + rb + (bc ^ swz_n));
            f32x4 f1 = *(f32x4*)((char*)wbase + rb + ((bc + 16) ^ swz_n));
            s8bf ah, al;
            #pragma unroll
            for (int j = 0; j < 4; ++j) {
                short h  = bf_hi(f0[j]); ah[j]     = h;  al[j]     = bf_hi(f0[j] - bf_to_f(h));
                short h2 = bf_hi(f1[j]); ah[4 + j] = h2; al[4 + j] = bf_hi(f1[j] - bf_to_f(h2));
            }
            #pragma unroll
            for (int nt = 0; nt < 4; ++nt) {
                acc2[nt] = __builtin_amdgcn_mfma_f32_16x16x32_bf16(ah, w2h[nt][k0i], acc2[nt], 0, 0, 0);
                acc2[nt] = __builtin_amdgcn_mfma_f32_16x16x32_bf16(ah, w2l[nt][k0i], acc2[nt], 0, 0, 0);
                acc2[nt] = __builtin_amdgcn_mfma_f32_16x16x32_bf16(al, w2h[nt][k0i], acc2[nt], 0, 0, 0);
            }
        }

        // ---- w = ssp(acc2 + b2) -> [16][256B] f32 swizzled (overlays h1) ----
        #pragma unroll
        for (int nt = 0; nt < 4; ++nt)
            #pragma unroll
            for (int r = 0; r < 4; ++r) {
                const int row = crow + r;
                *(float*)((char*)wbase + (row << 8) +
                          ((((nt * 16 + n16) << 2)) ^ ((row & 7) << 4))) =
                    ssp(acc2[nt][r] + b2v[nt]);
            }

        // ---- scatter: segmented reduce over sorted dst runs (scalar control) ----
        {
            float accv = 0.f;
            int cur = -1;
            #pragma unroll
            for (int e = 0; e < 16; ++e) {
                if (base + e < E) {                   // SALU-uniform
                    const int d = d_cur[e];
                    const float mv = *(const float*)((char*)wbase + (e << 8) +
                                         ((lane << 2) ^ ((e & 7) << 4))) * evs[e];
                    if (d != cur) {                   // uniform scc branch
                        if (cur >= 0) atomicAdd(&sums[(size_t)cur * 64 + lane], accv);
                        accv = mv; cur = d;
                    } else {
                        accv += mv;
                    }
                }
            }
            if (cur >= 0) atomicAdd(&sums[(size_t)cur * 64 + lane], accv);
        }

        // ---- rotate prefetched state in ----
        if (tn < ntiles) {
            #pragma unroll
            for (int e = 0; e < 16; ++e) { evs[e] = evs_n[e]; d_cur[e] = d_nxt[e]; }
        }
    }
}

// ---- node interaction block: h = sums/max(deg,1); out = ssp(h@W3+b3) ----
__global__ __launch_bounds__(256) void node_kernel(
    const float* __restrict__ sums, const int* __restrict__ hist,
    const float* __restrict__ W3, const float* __restrict__ b3,
    float* __restrict__ out, int N)
{
    __shared__ float sW[64][64];
    __shared__ float sb[64];
    __shared__ float sC[64];
    __shared__ float sX[64][65];

    const int tid = threadIdx.x;
    for (int i = tid; i < 4096; i += 256) sW[i >> 6][i & 63] = W3[i];
    if (tid < 64) sb[tid] = b3[tid];

    const int f4 = (tid & 15) << 2;
    const int e4 = (tid >> 4) << 2;
    const int ntiles = (N + 63) >> 6;

    for (int t = blockIdx.x; t < ntiles; t += gridDim.x) {
        const int base = t << 6;
        __syncthreads();
        if (tid < 64) {
            int gn = base + tid;
            sC[tid] = (gn < N) ? 1.0f / fmaxf((float)hist[gn], 1.0f) : 0.0f;
        }
        __syncthreads();
        #pragma unroll
        for (int k = 0; k < 16; ++k) {
            int idx = (k << 8) + tid;
            int n = idx >> 6, r = idx & 63;
            int gn = base + n;
            sX[n][r] = (gn < N) ? sums[(size_t)gn * 64 + r] * sC[n] : 0.0f;
        }
        __syncthreads();

        float acc[4][4] = {{0.f,0.f,0.f,0.f},{0.f,0.f,0.f,0.f},
                           {0.f,0.f,0.f,0.f},{0.f,0.f,0.f,0.f}};
        #pragma unroll 8
        for (int r = 0; r < 64; ++r) {
            float xv[4];
            #pragma unroll
            for (int i = 0; i < 4; ++i) xv[i] = sX[e4 + i][r];
            float4 w4 = *(const float4*)&sW[r][f4];
            #pragma unroll
            for (int i = 0; i < 4; ++i) {
                acc[i][0] = fmaf(xv[i], w4.x, acc[i][0]);
                acc[i][1] = fmaf(xv[i], w4.y, acc[i][1]);
                acc[i][2] = fmaf(xv[i], w4.z, acc[i][2]);
                acc[i][3] = fmaf(xv[i], w4.w, acc[i][3]);
            }
        }

        #pragma unroll
        for (int i = 0; i < 4; ++i) {
            int gn = base + e4 + i;
            if (gn < N) {
                float4 o;
                o.x = ssp(acc[i][0] + sb[f4 + 0]);
                o.y = ssp(acc[i][1] + sb[f4 + 1]);
                o.z = ssp(acc[i][2] + sb[f4 + 2]);
                o.w = ssp(acc[i][3] + sb[f4 + 3]);
                *(float4*)&out[(size_t)gn * 64 + f4] = o;
            }
        }
    }
}

extern "C" void kernel_launch(void* const* d_in, const int* in_sizes, int n_in,
                              void* d_out, int out_size, void* d_ws, size_t ws_size,
                              hipStream_t stream) {
    const float* bf = (const float*)d_in[0];
    const float* eh = (const float*)d_in[1];
    const float* W1 = (const float*)d_in[2];
    const float* b1 = (const float*)d_in[3];
    const float* W2 = (const float*)d_in[4];
    const float* b2 = (const float*)d_in[5];
    const float* W3 = (const float*)d_in[6];
    const float* b3 = (const float*)d_in[7];
    const int*   dst = (const int*)d_in[8];

    const int E = in_sizes[0] / 64;
    const int N = out_size / 64;        // out is [N, 64]

    // workspace: sums [N*64 f32] | hist [N i32] | cursor [N i32] | order [E i32] | bsum
    float* sums   = (float*)d_ws;
    int*   hist   = (int*)(sums + (size_t)N * 64);
    int*   cursor = hist + N;
    int*   order  = cursor + N;
    int*   bsum   = order + E;

    // zero sums + hist (cursor/order/bsum fully written by scan/rank)
    hipMemsetAsync(d_ws, 0, (size_t)N * 64 * sizeof(float) + N * sizeof(int), stream);

    const int gE = (E + 255) / 256;
    const int nb = (N + 1023) >> 10;
    hist_kernel<<<gE, 256, 0, stream>>>(dst, hist, E);
    scan_part<<<nb, 256, 0, stream>>>(hist, bsum, N);
    scan_top<<<1, 64, 0, stream>>>(bsum, nb);
    scan_local<<<nb, 256, 0, stream>>>(hist, bsum, cursor, N);
    rank_kernel<<<gE, 256, 0, stream>>>(dst, cursor, order, E);

    edge_kernel<<<2048, 256, 0, stream>>>(bf, eh, W1, b1, W2, b2, dst, order, sums, E);

    const int ntilesN = (N + 63) >> 6;
    node_kernel<<<ntilesN, 256, 0, stream>>>(sums, hist, W3, b3, (float*)d_out, N);
}